// Round 1
// baseline (840.876 us; speedup 1.0000x reference)
//
#include <hip/hip_runtime.h>

#define TILE 64
#define BK 16

#define B_ 4
#define T_ 1024
#define NH 12
#define HS 64
#define CDIM 768
#define QKVW 2304   // 3*CDIM

// ---------------- GEMM: C[M,N] = A[M,K] @ B[K,N] (+ R) -----------------
template<bool ADD_RES>
__global__ __launch_bounds__(256)
void gemm64(const float* __restrict__ A, const float* __restrict__ Bm,
            const float* __restrict__ R, float* __restrict__ C,
            int M, int N, int K) {
    __shared__ float As[BK][TILE + 4];   // [k][m], +4 pad keeps float4 reads 16B-aligned
    __shared__ float Bs[BK][TILE];       // [k][n]

    const int tid = threadIdx.x;
    const int tm  = tid >> 4;    // 0..15
    const int tn  = tid & 15;    // 0..15
    const int m0  = blockIdx.y * TILE;
    const int n0  = blockIdx.x * TILE;

    // staging indices
    const int am = tid >> 2;         // 0..63 (row within A tile)
    const int ak = (tid & 3) * 4;    // 0,4,8,12
    const int bk = tid >> 4;         // 0..15 (row within B tile)
    const int bn = (tid & 15) * 4;

    const float* Aptr = A + (size_t)(m0 + am) * K + ak;
    const float* Bptr = Bm + (size_t)bk * N + n0 + bn;

    float acc[4][4];
#pragma unroll
    for (int ii = 0; ii < 4; ++ii)
#pragma unroll
        for (int jj = 0; jj < 4; ++jj) acc[ii][jj] = 0.f;

    for (int k0 = 0; k0 < K; k0 += BK) {
        const float4 av = *(const float4*)(Aptr + k0);
        const float4 bv = *(const float4*)(Bptr + (size_t)k0 * N);
        __syncthreads();
        As[ak + 0][am] = av.x;
        As[ak + 1][am] = av.y;
        As[ak + 2][am] = av.z;
        As[ak + 3][am] = av.w;
        *(float4*)&Bs[bk][bn] = bv;
        __syncthreads();
#pragma unroll
        for (int kk = 0; kk < BK; ++kk) {
            const float4 a = *(const float4*)&As[kk][tm * 4];
            const float4 b = *(const float4*)&Bs[kk][tn * 4];
            const float ar[4] = {a.x, a.y, a.z, a.w};
            const float br[4] = {b.x, b.y, b.z, b.w};
#pragma unroll
            for (int ii = 0; ii < 4; ++ii)
#pragma unroll
                for (int jj = 0; jj < 4; ++jj)
                    acc[ii][jj] = fmaf(ar[ii], br[jj], acc[ii][jj]);
        }
    }

#pragma unroll
    for (int ii = 0; ii < 4; ++ii) {
        const int m = m0 + tm * 4 + ii;
        float4 out;
        out.x = acc[ii][0]; out.y = acc[ii][1]; out.z = acc[ii][2]; out.w = acc[ii][3];
        if (ADD_RES) {
            const float4 r = *(const float4*)(R + (size_t)m * N + n0 + tn * 4);
            out.x += r.x; out.y += r.y; out.z += r.z; out.w += r.w;
        }
        *(float4*)(C + (size_t)m * N + n0 + tn * 4) = out;
    }
}

// -------- per-64-element standardization (mean / unbiased std) ----------
__global__ __launch_bounds__(256)
void norm_kernel(float* __restrict__ qkv) {
    const int g    = blockIdx.x * 4 + (threadIdx.x >> 6);
    const int lane = threadIdx.x & 63;
    const size_t idx = (size_t)g * 64 + lane;
    const float v = qkv[idx];
    float s = v, ss = v * v;
#pragma unroll
    for (int off = 1; off < 64; off <<= 1) {
        s  += __shfl_xor(s,  off, 64);
        ss += __shfl_xor(ss, off, 64);
    }
    const float mu  = s * (1.0f / 64.0f);
    const float var = (ss - 64.0f * mu * mu) * (1.0f / 63.0f);
    const float rs  = rsqrtf(var);
    qkv[idx] = (v - mu) * rs;
}

// ----------------------------- scan -------------------------------------
// grid: 48 (b,h) pairs * 4 row-blocks = 192 blocks of 64 threads (1 wave).
// Each wave: 16 rows x 4 col-groups(16 cols). S row i independent given qkv:
// u = S k ; S = 0.99 S - 0.01 u k^T + k v^T ; o = S q.
__device__ __forceinline__ void load16(const float* __restrict__ p, float* d) {
    const float4 a = *(const float4*)(p + 0);
    const float4 b = *(const float4*)(p + 4);
    const float4 c = *(const float4*)(p + 8);
    const float4 e = *(const float4*)(p + 12);
    d[0]=a.x; d[1]=a.y; d[2]=a.z; d[3]=a.w;
    d[4]=b.x; d[5]=b.y; d[6]=b.z; d[7]=b.w;
    d[8]=c.x; d[9]=c.y; d[10]=c.z; d[11]=c.w;
    d[12]=e.x; d[13]=e.y; d[14]=e.z; d[15]=e.w;
}

__global__ __launch_bounds__(64)
void scan_kernel(const float* __restrict__ qkv, float* __restrict__ o) {
    const int bh = blockIdx.x >> 2;   // 0..47
    const int rb = blockIdx.x & 3;    // row block 0..3
    const int b  = bh / NH;
    const int h  = bh - b * NH;
    const int tid = threadIdx.x;      // 0..63
    const int r   = tid >> 2;         // 0..15
    const int cg  = tid & 3;          // 0..3
    const int i   = rb * 16 + r;      // state row 0..63
    const int j0  = cg * 16;          // first col

    const float* base = qkv + (size_t)b * T_ * QKVW + h * HS;
    float* ob = o + (size_t)b * T_ * CDIM + h * HS;

    float S[16];
#pragma unroll
    for (int z = 0; z < 16; ++z) S[z] = 0.f;

    float q0[16], k0[16], v0[16], ki0;
    float q1[16], k1[16], v1[16], ki1;

    // prefetch t=0
    {
        const float* p = base;
        load16(p + j0, q0);
        load16(p + CDIM + j0, k0);
        load16(p + 2 * CDIM + j0, v0);
        ki0 = p[CDIM + i];
    }

    for (int t = 0; t < T_; t += 2) {
        {   // prefetch t+1 (T_ even, always valid)
            const float* p = base + (size_t)(t + 1) * QKVW;
            load16(p + j0, q1);
            load16(p + CDIM + j0, k1);
            load16(p + 2 * CDIM + j0, v1);
            ki1 = p[CDIM + i];
        }
        {   // step t with buffer 0
            float u = 0.f;
#pragma unroll
            for (int z = 0; z < 16; ++z) u = fmaf(S[z], k0[z], u);
            u += __shfl_xor(u, 1, 64);
            u += __shfl_xor(u, 2, 64);
            const float bu = -0.01f * u;
            float ov = 0.f;
#pragma unroll
            for (int z = 0; z < 16; ++z) {
                const float sn = fmaf(bu, k0[z], fmaf(ki0, v0[z], 0.99f * S[z]));
                S[z] = sn;
                ov = fmaf(sn, q0[z], ov);
            }
            ov += __shfl_xor(ov, 1, 64);
            ov += __shfl_xor(ov, 2, 64);
            if (cg == 0) ob[(size_t)t * CDIM + i] = ov;
        }
        if (t + 2 < T_) {   // prefetch t+2
            const float* p = base + (size_t)(t + 2) * QKVW;
            load16(p + j0, q0);
            load16(p + CDIM + j0, k0);
            load16(p + 2 * CDIM + j0, v0);
            ki0 = p[CDIM + i];
        }
        {   // step t+1 with buffer 1
            float u = 0.f;
#pragma unroll
            for (int z = 0; z < 16; ++z) u = fmaf(S[z], k1[z], u);
            u += __shfl_xor(u, 1, 64);
            u += __shfl_xor(u, 2, 64);
            const float bu = -0.01f * u;
            float ov = 0.f;
#pragma unroll
            for (int z = 0; z < 16; ++z) {
                const float sn = fmaf(bu, k1[z], fmaf(ki1, v1[z], 0.99f * S[z]));
                S[z] = sn;
                ov = fmaf(sn, q1[z], ov);
            }
            ov += __shfl_xor(ov, 1, 64);
            ov += __shfl_xor(ov, 2, 64);
            if (cg == 0) ob[(size_t)(t + 1) * CDIM + i] = ov;
        }
    }
}

// ------------------------------ launch ----------------------------------
extern "C" void kernel_launch(void* const* d_in, const int* in_sizes, int n_in,
                              void* d_out, int out_size, void* d_ws, size_t ws_size,
                              hipStream_t stream) {
    const float* x      = (const float*)d_in[0];   // (4,1024,768)
    const float* w_attn = (const float*)d_in[1];   // (768, 2304)
    const float* w_proj = (const float*)d_in[2];   // (768, 768)
    float* out = (float*)d_out;                    // (4,1024,768)
    float* qkv = (float*)d_ws;                     // 4096 x 2304 fp32 = 37.75 MB
    float* y   = (float*)d_ws;                     // reuse after scan

    const int M = B_ * T_;   // 4096

    // 1) qkv = x @ w_attn
    gemm64<false><<<dim3(QKVW / TILE, M / TILE), 256, 0, stream>>>(
        x, w_attn, nullptr, qkv, M, QKVW, CDIM);

    // 2) standardize each 64-element (head-dim) group
    norm_kernel<<<(M * 3 * NH) / 4, 256, 0, stream>>>(qkv);

    // 3) sequential delta-rule scan -> o written into d_out (scratch for now)
    scan_kernel<<<48 * 4, 64, 0, stream>>>(qkv, out);

    // 4) y = o @ w_proj + x   (reads o from d_out, writes into ws)
    gemm64<true><<<dim3(CDIM / TILE, M / TILE), 256, 0, stream>>>(
        out, w_proj, x, y, M, CDIM, CDIM);

    // 5) final copy ws -> d_out
    hipMemcpyAsync(d_out, y, (size_t)M * CDIM * sizeof(float),
                   hipMemcpyDeviceToDevice, stream);
}